// Round 11
// baseline (233.275 us; speedup 1.0000x reference)
//
#include <hip/hip_runtime.h>
#include <math.h>

typedef float    floatx4 __attribute__((ext_vector_type(4)));
typedef _Float16 half8   __attribute__((ext_vector_type(8)));
typedef _Float16 half4v  __attribute__((ext_vector_type(4)));
typedef _Float16 half2v  __attribute__((ext_vector_type(2)));
typedef __fp16   fp16x2  __attribute__((ext_vector_type(2)));

constexpr int B    = 2;
constexpr int S    = 2048;
constexpr int NH   = 16;
constexpr int HD   = 64;
constexpr int DIM  = 1024;
constexpr int INNER = 1024;
constexpr int QKVN = 3072;
constexpr int NTOK = 4096;
constexpr float EPS = 1e-5f;
constexpr float MAX_SCALE = 10.0f;
constexpr float SCALE_LOG2E = 0.125f * 1.4426950408889634f;

#define MFMA16(a, b, c) __builtin_amdgcn_mfma_f32_16x16x16f16((a), (b), (c), 0, 0, 0)

__device__ __forceinline__ half2v pkrtz(float a, float b) {
  fp16x2 t = __builtin_amdgcn_cvt_pkrtz(a, b);
  return __builtin_bit_cast(half2v, t);
}
__device__ __forceinline__ half2v hmax2(half2v a, half2v b) {
  return __builtin_elementwise_max(a, b);
}
__device__ __forceinline__ half8 cvt8(float4 a, float4 b) {
  half2v p0 = pkrtz(a.x, a.y), p1 = pkrtz(a.z, a.w);
  half2v p2 = pkrtz(b.x, b.y), p3 = pkrtz(b.z, b.w);
  half4v q0 = __builtin_shufflevector(p0, p1, 0, 1, 2, 3);
  half4v q1 = __builtin_shufflevector(p2, p3, 0, 1, 2, 3);
  return __builtin_shufflevector(q0, q1, 0, 1, 2, 3, 4, 5, 6, 7);
}

// ---------------------------------------------------------------------------
// Fused prep: weight transposes only (hs convert now fused into gemm1).
// blockIdx [0,768) transpose w_qkv; [768,1024) transpose w_out.
// ---------------------------------------------------------------------------
__device__ __forceinline__ void transpose_tile(const float* __restrict__ w,
                                               _Float16* __restrict__ wT,
                                               int K, int N, int k0, int n0,
                                               _Float16* T, int tid) {
#pragma unroll
  for (int i = 0; i < 4; ++i) {
    int id = tid + 256 * i;
    int r = id >> 4, c = id & 15;
    float4 v = *(const float4*)&w[(size_t)(k0 + r) * N + n0 + c * 4];
    half4v s; s[0] = (_Float16)v.x; s[1] = (_Float16)v.y;
    s[2] = (_Float16)v.z; s[3] = (_Float16)v.w;
    *(half4v*)&T[r * 72 + c * 4] = s;
  }
  __syncthreads();
#pragma unroll
  for (int i = 0; i < 2; ++i) {
    int id = tid + 256 * i;
    int n = id >> 3, cs = id & 7;
    half8 o;
#pragma unroll
    for (int jj = 0; jj < 8; ++jj) o[jj] = T[(cs * 8 + jj) * 72 + n];
    *(half8*)&wT[(size_t)(n0 + n) * K + k0 + cs * 8] = o;
  }
}

__global__ __launch_bounds__(256)
void prep_all(const float* __restrict__ w_qkv, const float* __restrict__ w_out,
              _Float16* __restrict__ wqkvT, _Float16* __restrict__ woutT) {
  __shared__ _Float16 T[64 * 72];
  const int bx = blockIdx.x, tid = threadIdx.x;
  if (bx < 768) {             // w_qkv: 48 n-tiles x 16 k-tiles
    transpose_tile(w_qkv, wqkvT, DIM, QKVN, (bx / 48) * 64, (bx % 48) * 64, T, tid);
  } else {                    // w_out: 16 x 16
    int id = bx - 768;
    transpose_tile(w_out, woutT, INNER, DIM, (id / 16) * 64, (id % 16) * 64, T, tid);
  }
}

// ---------------------------------------------------------------------------
// fp16 MFMA GEMM with register-prefetch staging. A may be fp32 (converted
// in-register at ds_write time) or f16.
// ---------------------------------------------------------------------------
template<bool A_F32, bool OUT_F16, typename OutT>
__global__ __launch_bounds__(256)
void gemm_bt(const void* __restrict__ Av, const _Float16* __restrict__ BT,
             const float* __restrict__ bias, OutT* __restrict__ C, int N, int K) {
  __shared__ _Float16 As[128 * 56];
  __shared__ _Float16 Bs[128 * 56];
  const float*    Af = (const float*)Av;
  const _Float16* Ah = (const _Float16*)Av;
  const int tid = threadIdx.x;
  const int wave = tid >> 6, lane = tid & 63, quad = lane >> 4, l16 = lane & 15;
  const int wm = wave >> 1, wn = wave & 1;
  const int m0 = blockIdx.y * 128, n0 = blockIdx.x * 128;

  const int id0 = tid, id1 = tid + 256;
  const int m_0 = id0 >> 2, c_0 = (id0 & 3) * 8;
  const int m_1 = id1 >> 2, c_1 = (id1 & 3) * 8;
  const size_t a0 = (size_t)(m0 + m_0) * K + c_0;
  const size_t a1 = (size_t)(m0 + m_1) * K + c_1;
  const _Float16* Bp0 = BT + (size_t)(n0 + m_0) * K + c_0;
  const _Float16* Bp1 = BT + (size_t)(n0 + m_1) * K + c_1;

  half8 ar0, ar1;
  float4 f0a, f0b, f1a, f1b;
  if constexpr (A_F32) {
    f0a = *(const float4*)&Af[a0]; f0b = *(const float4*)&Af[a0 + 4];
    f1a = *(const float4*)&Af[a1]; f1b = *(const float4*)&Af[a1 + 4];
  } else {
    ar0 = *(const half8*)&Ah[a0];
    ar1 = *(const half8*)&Ah[a1];
  }
  half8 br0 = *(const half8*)Bp0, br1 = *(const half8*)Bp1;

  floatx4 acc[4][4] = {};

  for (int k0 = 0; k0 < K; k0 += 32) {
    __syncthreads();
    if constexpr (A_F32) {
      *(half8*)&As[m_0 * 56 + c_0] = cvt8(f0a, f0b);
      *(half8*)&As[m_1 * 56 + c_1] = cvt8(f1a, f1b);
    } else {
      *(half8*)&As[m_0 * 56 + c_0] = ar0;
      *(half8*)&As[m_1 * 56 + c_1] = ar1;
    }
    *(half8*)&Bs[m_0 * 56 + c_0] = br0;
    *(half8*)&Bs[m_1 * 56 + c_1] = br1;
    if (k0 + 32 < K) {
      if constexpr (A_F32) {
        f0a = *(const float4*)&Af[a0 + k0 + 32]; f0b = *(const float4*)&Af[a0 + k0 + 36];
        f1a = *(const float4*)&Af[a1 + k0 + 32]; f1b = *(const float4*)&Af[a1 + k0 + 36];
      } else {
        ar0 = *(const half8*)&Ah[a0 + k0 + 32];
        ar1 = *(const half8*)&Ah[a1 + k0 + 32];
      }
      br0 = *(const half8*)(Bp0 + k0 + 32);
      br1 = *(const half8*)(Bp1 + k0 + 32);
    }
    __syncthreads();
    half8 a[4], b[4];
#pragma unroll
    for (int i = 0; i < 4; ++i)
      a[i] = *(const half8*)&As[(wm * 64 + i * 16 + l16) * 56 + quad * 8];
#pragma unroll
    for (int j = 0; j < 4; ++j)
      b[j] = *(const half8*)&Bs[(wn * 64 + j * 16 + l16) * 56 + quad * 8];
#pragma unroll
    for (int i = 0; i < 4; ++i)
#pragma unroll
      for (int j = 0; j < 4; ++j)
        acc[i][j] = __builtin_amdgcn_mfma_f32_16x16x32_f16(a[i], b[j], acc[i][j], 0, 0, 0);
  }

  const int rb = m0 + wm * 64 + quad * 4;
  const int cb = n0 + wn * 64 + l16;
#pragma unroll
  for (int j = 0; j < 4; ++j) {
    const float bj = bias[cb + j * 16];
#pragma unroll
    for (int i = 0; i < 4; ++i) {
#pragma unroll
      for (int r = 0; r < 4; ++r) {
        float v = acc[i][j][r] + bj;
        size_t idx = (size_t)(rb + i * 16 + r) * N + cb + j * 16;
        if constexpr (OUT_F16) C[idx] = (_Float16)v; else C[idx] = v;
      }
    }
  }
}

// ---------------------------------------------------------------------------
// Fused post: blockIdx [0,4096) = per-token RMSNorm+rotary+hist-scale;
// [4096,5120) = V transpose/swizzle tiles.
// ---------------------------------------------------------------------------
__global__ __launch_bounds__(256)
void post_all(const _Float16* __restrict__ qkvh, const float* __restrict__ rot,
              const float* __restrict__ nqw, const float* __restrict__ nkw,
              const float* __restrict__ hks, const int* __restrict__ octx,
              _Float16* __restrict__ qo_, _Float16* __restrict__ ko_,
              _Float16* __restrict__ vt) {
  __shared__ __align__(16) char arena[64 * 72 * 2];
  const int tid = threadIdx.x;
  if (blockIdx.x < 4096) {
    float* red = (float*)arena;
    const int token = blockIdx.x;
    const int b = token >> 11, spos = token & (S - 1);
    const _Float16* qrow = qkvh + (size_t)token * QKVN;
    const _Float16* krow = qrow + INNER;
    const float* r = rot + (size_t)token * (2 * HD);

    const int e0 = tid * 4;
    half4v qs = *(const half4v*)(qrow + e0);
    half4v ks = *(const half4v*)(krow + e0);
    float q4[4], k4[4];
#pragma unroll
    for (int i = 0; i < 4; ++i) { q4[i] = (float)qs[i]; k4[i] = (float)ks[i]; }

    float sq = 0.f, sk = 0.f;
#pragma unroll
    for (int i = 0; i < 4; ++i) { sq += q4[i] * q4[i]; sk += k4[i] * k4[i]; }
#pragma unroll
    for (int msk = 1; msk < 64; msk <<= 1) {
      sq += __shfl_xor(sq, msk);
      sk += __shfl_xor(sk, msk);
    }
    const int wv = tid >> 6;
    if ((tid & 63) == 0) { red[wv] = sq; red[4 + wv] = sk; }
    __syncthreads();
    sq = red[0] + red[1] + red[2] + red[3];
    sk = red[4] + red[5] + red[6] + red[7];

    const float qinv = 1.0f / sqrtf(sq * (1.0f / INNER) + EPS);
    const float kinv = 1.0f / sqrtf(sk * (1.0f / INNER) + EPS);

#pragma unroll
    for (int i = 0; i < 4; ++i) {
      q4[i] = q4[i] * qinv * nqw[e0 + i];
      k4[i] = k4[i] * kinv * nkw[e0 + i];
    }

    const int h = e0 >> 6, d0 = e0 & (HD - 1);
    const float c0 = r[d0],     s0 = r[HD + d0 + 1];
    const float c1 = r[d0 + 2], s1 = r[HD + d0 + 3];

    float qo[4], ko[4];
    qo[0] = q4[0] * c0 - q4[1] * s0;
    qo[1] = q4[0] * s0 + q4[1] * c0;
    qo[2] = q4[2] * c1 - q4[3] * s1;
    qo[3] = q4[2] * s1 + q4[3] * c1;
    ko[0] = k4[0] * c0 - k4[1] * s0;
    ko[1] = k4[0] * s0 + k4[1] * c0;
    ko[2] = k4[2] * c1 - k4[3] * s1;
    ko[3] = k4[2] * s1 + k4[3] * c1;

    const int hist = S - octx[0];
    if (hist > 0 && spos < hist) {
      const float sig = 1.0f / (1.0f + expf(-hks[h]));
      const float sc = 1.0f + sig * (MAX_SCALE - 1.0f);
#pragma unroll
      for (int i = 0; i < 4; ++i) ko[i] *= sc;
    }

    half4v qo4, ko4;
#pragma unroll
    for (int i = 0; i < 4; ++i) {
      qo4[i] = (_Float16)(qo[i] * SCALE_LOG2E);
      ko4[i] = (_Float16)ko[i];
    }
    const size_t obase = ((size_t)(b * NH + h) * S + spos) * HD + d0;
    *(half4v*)(qo_ + obase) = qo4;
    *(half4v*)(ko_ + obase) = ko4;
  } else {
    _Float16* T = (_Float16*)arena;
    const int id = blockIdx.x - 4096;
    const int bh = id & 31, kt = id >> 5;
    const int b = bh >> 4, h = bh & 15;
    const int s0 = kt * 64;
#pragma unroll
    for (int i = 0; i < 2; ++i) {
      int id2 = tid + 256 * i;
      int s = id2 >> 3, c = id2 & 7;
      *(half8*)&T[s * 72 + c * 8] =
          *(const half8*)&qkvh[(size_t)(b * S + s0 + s) * QKVN + 2 * INNER + h * HD + c * 8];
    }
    __syncthreads();
    _Float16* orow = vt + ((size_t)bh * 32 + kt) * 64 * 64;
#pragma unroll
    for (int i = 0; i < 4; ++i) {
      int id2 = tid + 256 * i;
      int d = id2 >> 4, g = id2 & 15;
      int quad = g >> 2, jj = g & 3;
      half4v o;
#pragma unroll
      for (int k = 0; k < 4; ++k) o[k] = T[(jj * 16 + quad * 4 + k) * 72 + d];
      *(half4v*)&orow[d * 64 + g * 4] = o;
    }
  }
}

// ---------------------------------------------------------------------------
// MFMA flash attention: 512 thr = 8 waves cover a 128-row Q tile, split-K
// over 2 partitions (blockIdx.z, 16 K-tiles each) for 4 blocks/CU occupancy.
// Double-buffered LDS + register prefetch; packed-f16 softmax. Emits
// normalized partial O (f16) + per-row (m,l) for the merge kernel.
// ---------------------------------------------------------------------------
__global__ __launch_bounds__(512)
void attn_mfma(const _Float16* __restrict__ qb, const _Float16* __restrict__ kb,
               const _Float16* __restrict__ vt, _Float16* __restrict__ On,
               float2* __restrict__ ml) {
  __shared__ _Float16 Kb0[64 * 72], Vb0[64 * 72];
  __shared__ _Float16 Kb1[64 * 72], Vb1[64 * 72];
  const int bh = blockIdx.x;
  const int q0 = blockIdx.y * 128;
  const int part = blockIdx.z;
  const int tid = threadIdx.x;
  const int wave = tid >> 6, lane = tid & 63, quad = lane >> 4, l16 = lane & 15;

  const _Float16* qbh = qb + (size_t)bh * S * HD;
  const _Float16* kbh = kb + (size_t)bh * S * HD;
  const _Float16* vbh = vt + (size_t)bh * S * HD;

  half8 aq[2];
#pragma unroll
  for (int ks = 0; ks < 2; ++ks)
    aq[ks] = *(const half8*)&qbh[(size_t)(q0 + wave * 16 + l16) * HD + ks * 32 + quad * 8];

  const int rr = tid >> 3, cc = (tid & 7) * 8;
  const int kt0 = part * 16;
  const _Float16* kptr = kbh + (size_t)(kt0 * 64 + rr) * HD + cc;
  const _Float16* vptr = vbh + ((size_t)kt0 * 64 + rr) * 64 + cc;

  half8 kreg = *(const half8*)kptr, vreg = *(const half8*)vptr;   // tile kt0
  *(half8*)&Kb0[rr * 72 + cc] = kreg;
  *(half8*)&Vb0[rr * 72 + cc] = vreg;
  kptr += 64 * HD; vptr += 64 * 64;
  kreg = *(const half8*)kptr; vreg = *(const half8*)vptr;         // tile kt0+1
  __syncthreads();

  floatx4 o16[4] = {};
  float mrow = -INFINITY, lrow = 0.f;

  auto compute = [&](const _Float16* Kp, const _Float16* Vp) {
    floatx4 sc[4] = {};
#pragma unroll
    for (int jj = 0; jj < 4; ++jj) {
#pragma unroll
      for (int ks = 0; ks < 2; ++ks) {
        half8 ak = *(const half8*)&Kp[(jj * 16 + l16) * 72 + ks * 32 + quad * 8];
        sc[jj] = __builtin_amdgcn_mfma_f32_16x16x32_f16(ak, aq[ks], sc[jj], 0, 0, 0);
      }
    }

    half2v ph[8];
#pragma unroll
    for (int jj = 0; jj < 4; ++jj) {
      ph[jj * 2]     = pkrtz(sc[jj][0], sc[jj][1]);
      ph[jj * 2 + 1] = pkrtz(sc[jj][2], sc[jj][3]);
    }
    half2v m0 = hmax2(hmax2(ph[0], ph[1]), hmax2(ph[2], ph[3]));
    half2v m1 = hmax2(hmax2(ph[4], ph[5]), hmax2(ph[6], ph[7]));
    half2v mx2 = hmax2(m0, m1);
    int mi = __builtin_bit_cast(int, mx2);
    mx2 = hmax2(mx2, __builtin_bit_cast(half2v, __shfl_xor(mi, 16)));
    mi = __builtin_bit_cast(int, mx2);
    mx2 = hmax2(mx2, __builtin_bit_cast(half2v, __shfl_xor(mi, 32)));
    const float mxf = fmaxf((float)mx2[0], (float)mx2[1]);
    const float mn = fmaxf(mrow, mxf);
    const bool up = mn > mrow;
    const float alpha = up ? exp2f(mrow - mn) : 1.0f;
    mrow = mn;

    const _Float16 mnh = (_Float16)mn;
    half2v mn2; mn2[0] = mnh; mn2[1] = mnh;
    half2v pe[8];
#pragma unroll
    for (int i = 0; i < 8; ++i)
      pe[i] = __builtin_elementwise_exp2(ph[i] - mn2);

    half2v one2; one2[0] = (_Float16)1.f; one2[1] = (_Float16)1.f;
    const fp16x2 one2p = __builtin_bit_cast(fp16x2, one2);
    float rs = 0.f;
#pragma unroll
    for (int i = 0; i < 8; ++i)
      rs = __builtin_amdgcn_fdot2(__builtin_bit_cast(fp16x2, pe[i]), one2p, rs, false);
    rs += __shfl_xor(rs, 16);
    rs += __shfl_xor(rs, 32);
    lrow = lrow * alpha + rs;

    if (__ballot(up)) {
      float alr[4];
#pragma unroll
      for (int r = 0; r < 4; ++r) alr[r] = __shfl(alpha, quad * 4 + r);
#pragma unroll
      for (int jb = 0; jb < 4; ++jb)
#pragma unroll
        for (int r = 0; r < 4; ++r) o16[jb][r] *= alr[r];
    }

    half4v ap[4];
#pragma unroll
    for (int jj = 0; jj < 4; ++jj)
      ap[jj] = __builtin_shufflevector(pe[jj * 2], pe[jj * 2 + 1], 0, 1, 2, 3);

#pragma unroll
    for (int jb = 0; jb < 4; ++jb) {
      half8 v01 = *(const half8*)&Vp[(jb * 16 + l16) * 72 + quad * 16];
      half8 v23 = *(const half8*)&Vp[(jb * 16 + l16) * 72 + quad * 16 + 8];
      half4v b0 = __builtin_shufflevector(v01, v01, 0, 1, 2, 3);
      half4v b1 = __builtin_shufflevector(v01, v01, 4, 5, 6, 7);
      half4v b2 = __builtin_shufflevector(v23, v23, 0, 1, 2, 3);
      half4v b3 = __builtin_shufflevector(v23, v23, 4, 5, 6, 7);
      o16[jb] = MFMA16(ap[0], b0, o16[jb]);
      o16[jb] = MFMA16(ap[1], b1, o16[jb]);
      o16[jb] = MFMA16(ap[2], b2, o16[jb]);
      o16[jb] = MFMA16(ap[3], b3, o16[jb]);
    }
  };

  for (int t = 0; t < 16; t += 2) {
    *(half8*)&Kb1[rr * 72 + cc] = kreg;
    *(half8*)&Vb1[rr * 72 + cc] = vreg;
    if (t + 2 < 16) {
      kptr += 64 * HD; vptr += 64 * 64;
      kreg = *(const half8*)kptr; vreg = *(const half8*)vptr;
    }
    compute(Kb0, Vb0);
    __syncthreads();
    if (t + 2 < 16) {
      *(half8*)&Kb0[rr * 72 + cc] = kreg;
      *(half8*)&Vb0[rr * 72 + cc] = vreg;
      if (t + 3 < 16) {
        kptr += 64 * HD; vptr += 64 * 64;
        kreg = *(const half8*)kptr; vreg = *(const half8*)vptr;
      }
    }
    compute(Kb1, Vb1);
    __syncthreads();
  }

  // epilogue: normalized partial O + (m,l) per row
  float linv[4];
#pragma unroll
  for (int r = 0; r < 4; ++r) linv[r] = 1.0f / __shfl(lrow, quad * 4 + r);
  const size_t pb = (size_t)(part * 32 + bh) * S;
#pragma unroll
  for (int jb = 0; jb < 4; ++jb) {
#pragma unroll
    for (int r = 0; r < 4; ++r) {
      const int row = q0 + wave * 16 + quad * 4 + r;
      On[(pb + row) * HD + jb * 16 + l16] = (_Float16)(o16[jb][r] * linv[r]);
    }
  }
  if (quad == 0)
    ml[pb + q0 + wave * 16 + l16] = make_float2(mrow, lrow);
}

// ---------------------------------------------------------------------------
// Merge 2 split-K partitions: O = w1*O1n + w2*O2n, w_i = exp2(m_i-m*)*l_i
// normalized. Writes attnb in [b*S+s][h*64+d] layout.
// ---------------------------------------------------------------------------
__global__ __launch_bounds__(256)
void attn_merge(const _Float16* __restrict__ On, const float2* __restrict__ ml,
                _Float16* __restrict__ attnb) {
  const int id = blockIdx.x * 256 + threadIdx.x;   // 524288 total
  const int d8 = id & 7;
  const int h  = (id >> 3) & 15;
  const int s  = (id >> 7) & 2047;
  const int b  = id >> 18;
  const int bh = b * 16 + h;
  const float2 m1 = ml[(size_t)bh * S + s];
  const float2 m2 = ml[(size_t)(32 + bh) * S + s];
  const float mm = fmaxf(m1.x, m2.x);
  float w1 = exp2f(m1.x - mm) * m1.y;
  float w2 = exp2f(m2.x - mm) * m2.y;
  const float inv = 1.0f / (w1 + w2);
  w1 *= inv; w2 *= inv;
  const half8 o1 = *(const half8*)&On[((size_t)bh * S + s) * HD + d8 * 8];
  const half8 o2 = *(const half8*)&On[((size_t)(32 + bh) * S + s) * HD + d8 * 8];
  half8 o;
#pragma unroll
  for (int j = 0; j < 8; ++j)
    o[j] = (_Float16)(w1 * (float)o1[j] + w2 * (float)o2[j]);
  *(half8*)&attnb[((size_t)(b * S + s)) * INNER + h * HD + d8 * 8] = o;
}

// ---------------------------------------------------------------------------
extern "C" void kernel_launch(void* const* d_in, const int* in_sizes, int n_in,
                              void* d_out, int out_size, void* d_ws, size_t ws_size,
                              hipStream_t stream) {
  const float* hs    = (const float*)d_in[0];
  const float* rot   = (const float*)d_in[1];
  const float* w_qkv = (const float*)d_in[2];
  const float* b_qkv = (const float*)d_in[3];
  const float* nqw   = (const float*)d_in[4];
  const float* nkw   = (const float*)d_in[5];
  const float* w_out = (const float*)d_in[6];
  const float* b_out = (const float*)d_in[7];
  const float* hks   = (const float*)d_in[8];
  const int*   octx  = (const int*)d_in[9];

  _Float16* attnb = (_Float16*)d_ws;                 // 0-8 MiB
  _Float16* wqkvT = attnb + (size_t)NTOK * DIM;      // 8-14 MiB
  _Float16* woutT = wqkvT + (size_t)QKVN * DIM;      // 14-16 MiB
  _Float16* qkvh  = woutT + (size_t)DIM * INNER;     // 16-40 MiB
  _Float16* q_h   = qkvh  + (size_t)NTOK * QKVN;     // 40-48 MiB
  _Float16* k_h   = q_h   + (size_t)B * NH * S * HD; // 48-56 MiB
  _Float16* vT    = k_h   + (size_t)B * NH * S * HD; // 56-64 MiB
  // split-K partials alias qkvh (dead after post_all): On 16.8 MiB + ml 1 MiB
  _Float16* On    = qkvh;
  float2*   ml    = (float2*)(qkvh + (size_t)2 * B * NH * S * HD);

  prep_all<<<1024, 256, 0, stream>>>(w_qkv, w_out, wqkvT, woutT);

  gemm_bt<true, true, _Float16><<<dim3(QKVN / 128, NTOK / 128), 256, 0, stream>>>(
      hs, wqkvT, b_qkv, qkvh, QKVN, DIM);

  post_all<<<5120, 256, 0, stream>>>(qkvh, rot, nqw, nkw, hks, octx, q_h, k_h, vT);

  attn_mfma<<<dim3(B * NH, S / 128, 2), 512, 0, stream>>>(q_h, k_h, vT, On, ml);
  attn_merge<<<(B * S * NH * 8) / 256, 256, 0, stream>>>(On, ml, attnb);

  gemm_bt<false, false, float><<<dim3(DIM / 128, NTOK / 128), 256, 0, stream>>>(
      attnb, woutT, b_out, (float*)d_out, DIM, INNER);
}

// Round 12
// 231.458 us; speedup vs baseline: 1.0079x; 1.0079x over previous
//
#include <hip/hip_runtime.h>
#include <math.h>

typedef float    floatx4  __attribute__((ext_vector_type(4)));
typedef float    floatx16 __attribute__((ext_vector_type(16)));
typedef _Float16 half8    __attribute__((ext_vector_type(8)));
typedef _Float16 half4v   __attribute__((ext_vector_type(4)));
typedef _Float16 half2v   __attribute__((ext_vector_type(2)));
typedef __fp16   fp16x2   __attribute__((ext_vector_type(2)));

constexpr int B    = 2;
constexpr int S    = 2048;
constexpr int NH   = 16;
constexpr int HD   = 64;
constexpr int DIM  = 1024;
constexpr int INNER = 1024;
constexpr int QKVN = 3072;
constexpr int NTOK = 4096;
constexpr float EPS = 1e-5f;
constexpr float MAX_SCALE = 10.0f;
constexpr float SCALE_LOG2E = 0.125f * 1.4426950408889634f;

#define MFMA16(a, b, c) __builtin_amdgcn_mfma_f32_16x16x16f16((a), (b), (c), 0, 0, 0)
#define MFMA32(a, b, c) __builtin_amdgcn_mfma_f32_32x32x16_f16((a), (b), (c), 0, 0, 0)

__device__ __forceinline__ half2v pkrtz(float a, float b) {
  fp16x2 t = __builtin_amdgcn_cvt_pkrtz(a, b);
  return __builtin_bit_cast(half2v, t);
}
__device__ __forceinline__ half2v hmax2(half2v a, half2v b) {
  return __builtin_elementwise_max(a, b);
}

// ---------------------------------------------------------------------------
// Fused prep: blockIdx [0,2048) fp32->fp16 convert of hs;
// [2048,2816) transpose w_qkv; [2816,3072) transpose w_out.  (R10 form)
// ---------------------------------------------------------------------------
__device__ __forceinline__ void transpose_tile(const float* __restrict__ w,
                                               _Float16* __restrict__ wT,
                                               int K, int N, int k0, int n0,
                                               _Float16* T, int tid) {
#pragma unroll
  for (int i = 0; i < 4; ++i) {
    int id = tid + 256 * i;
    int r = id >> 4, c = id & 15;
    float4 v = *(const float4*)&w[(size_t)(k0 + r) * N + n0 + c * 4];
    half4v s; s[0] = (_Float16)v.x; s[1] = (_Float16)v.y;
    s[2] = (_Float16)v.z; s[3] = (_Float16)v.w;
    *(half4v*)&T[r * 72 + c * 4] = s;
  }
  __syncthreads();
#pragma unroll
  for (int i = 0; i < 2; ++i) {
    int id = tid + 256 * i;
    int n = id >> 3, cs = id & 7;
    half8 o;
#pragma unroll
    for (int jj = 0; jj < 8; ++jj) o[jj] = T[(cs * 8 + jj) * 72 + n];
    *(half8*)&wT[(size_t)(n0 + n) * K + k0 + cs * 8] = o;
  }
}

__global__ __launch_bounds__(256)
void prep_all(const float* __restrict__ hs, const float* __restrict__ w_qkv,
              const float* __restrict__ w_out, _Float16* __restrict__ hsb,
              _Float16* __restrict__ wqkvT, _Float16* __restrict__ woutT) {
  __shared__ _Float16 T[64 * 72];
  const int bx = blockIdx.x, tid = threadIdx.x;
  if (bx < 2048) {
    int id = bx * 256 + tid;
    const float4 a = ((const float4*)hs)[id * 2];
    const float4 b = ((const float4*)hs)[id * 2 + 1];
    half8 o;
    o[0] = (_Float16)a.x; o[1] = (_Float16)a.y; o[2] = (_Float16)a.z; o[3] = (_Float16)a.w;
    o[4] = (_Float16)b.x; o[5] = (_Float16)b.y; o[6] = (_Float16)b.z; o[7] = (_Float16)b.w;
    ((half8*)hsb)[id] = o;
  } else if (bx < 2816) {
    int id = bx - 2048;
    transpose_tile(w_qkv, wqkvT, DIM, QKVN, (id / 48) * 64, (id % 48) * 64, T, tid);
  } else {
    int id = bx - 2816;
    transpose_tile(w_out, woutT, INNER, DIM, (id / 16) * 64, (id % 16) * 64, T, tid);
  }
}

// ---------------------------------------------------------------------------
// fp16 MFMA GEMM, register-prefetch staging, now on 32x32x16 MFMA:
// wave owns 64x64 as 2x2 of 32x32 (half the MFMA instructions at higher
// FLOP/cyc vs 16x16x32; identical LDS traffic).
// C/D layout: col=lane&31, row=(reg&3)+8*(reg>>2)+4*(lane>>5)  [HW-verified]
// A/B frag:   m(or n)=lane&31, k=(lane>>5)*8 + j  -> contiguous b128 reads.
// ---------------------------------------------------------------------------
template<bool OUT_F16, typename OutT>
__global__ __launch_bounds__(256)
void gemm_bt(const _Float16* __restrict__ A, const _Float16* __restrict__ BT,
             const float* __restrict__ bias, OutT* __restrict__ C, int N, int K) {
  __shared__ _Float16 As[128 * 56];
  __shared__ _Float16 Bs[128 * 56];
  const int tid = threadIdx.x;
  const int wave = tid >> 6, lane = tid & 63;
  const int l32 = lane & 31, lh = lane >> 5;
  const int wm = wave >> 1, wn = wave & 1;
  const int m0 = blockIdx.y * 128, n0 = blockIdx.x * 128;

  const int id0 = tid, id1 = tid + 256;
  const int m_0 = id0 >> 2, c_0 = (id0 & 3) * 8;
  const int m_1 = id1 >> 2, c_1 = (id1 & 3) * 8;
  const _Float16* Ap0 = A + (size_t)(m0 + m_0) * K + c_0;
  const _Float16* Ap1 = A + (size_t)(m0 + m_1) * K + c_1;
  const _Float16* Bp0 = BT + (size_t)(n0 + m_0) * K + c_0;
  const _Float16* Bp1 = BT + (size_t)(n0 + m_1) * K + c_1;

  half8 ar0 = *(const half8*)Ap0, ar1 = *(const half8*)Ap1;
  half8 br0 = *(const half8*)Bp0, br1 = *(const half8*)Bp1;

  floatx16 acc[2][2] = {};

  for (int k0 = 0; k0 < K; k0 += 32) {
    __syncthreads();
    *(half8*)&As[m_0 * 56 + c_0] = ar0;
    *(half8*)&As[m_1 * 56 + c_1] = ar1;
    *(half8*)&Bs[m_0 * 56 + c_0] = br0;
    *(half8*)&Bs[m_1 * 56 + c_1] = br1;
    if (k0 + 32 < K) {
      ar0 = *(const half8*)(Ap0 + k0 + 32);
      ar1 = *(const half8*)(Ap1 + k0 + 32);
      br0 = *(const half8*)(Bp0 + k0 + 32);
      br1 = *(const half8*)(Bp1 + k0 + 32);
    }
    __syncthreads();
    half8 a[2][2], b[2][2];   // [bi or bj][k16-substep s]
#pragma unroll
    for (int bi = 0; bi < 2; ++bi)
#pragma unroll
      for (int s = 0; s < 2; ++s) {
        a[bi][s] = *(const half8*)&As[(wm * 64 + bi * 32 + l32) * 56 + s * 16 + lh * 8];
        b[bi][s] = *(const half8*)&Bs[(wn * 64 + bi * 32 + l32) * 56 + s * 16 + lh * 8];
      }
#pragma unroll
    for (int bi = 0; bi < 2; ++bi)
#pragma unroll
      for (int bj = 0; bj < 2; ++bj) {
        acc[bi][bj] = MFMA32(a[bi][0], b[bj][0], acc[bi][bj]);
        acc[bi][bj] = MFMA32(a[bi][1], b[bj][1], acc[bi][bj]);
      }
  }

  const int rb = m0 + wm * 64;
  const int cb = n0 + wn * 64;
  const float bj0 = bias[cb + l32];
  const float bj1 = bias[cb + 32 + l32];
#pragma unroll
  for (int bi = 0; bi < 2; ++bi) {
#pragma unroll
    for (int bj = 0; bj < 2; ++bj) {
      const float bb = bj ? bj1 : bj0;
#pragma unroll
      for (int r = 0; r < 16; ++r) {
        const int row = rb + bi * 32 + (r & 3) + 8 * (r >> 2) + 4 * lh;
        const int col = cb + bj * 32 + l32;
        float v = acc[bi][bj][r] + bb;
        size_t idx = (size_t)row * N + col;
        if constexpr (OUT_F16) C[idx] = (_Float16)v; else C[idx] = v;
      }
    }
  }
}

// ---------------------------------------------------------------------------
// Fused post: blockIdx [0,4096) = per-token RMSNorm+rotary+hist-scale;
// [4096,5120) = V transpose/swizzle tiles.  (R10 form)
// ---------------------------------------------------------------------------
__global__ __launch_bounds__(256)
void post_all(const _Float16* __restrict__ qkvh, const float* __restrict__ rot,
              const float* __restrict__ nqw, const float* __restrict__ nkw,
              const float* __restrict__ hks, const int* __restrict__ octx,
              _Float16* __restrict__ qo_, _Float16* __restrict__ ko_,
              _Float16* __restrict__ vt) {
  __shared__ __align__(16) char arena[64 * 72 * 2];
  const int tid = threadIdx.x;
  if (blockIdx.x < 4096) {
    float* red = (float*)arena;
    const int token = blockIdx.x;
    const int b = token >> 11, spos = token & (S - 1);
    const _Float16* qrow = qkvh + (size_t)token * QKVN;
    const _Float16* krow = qrow + INNER;
    const float* r = rot + (size_t)token * (2 * HD);

    const int e0 = tid * 4;
    half4v qs = *(const half4v*)(qrow + e0);
    half4v ks = *(const half4v*)(krow + e0);
    float q4[4], k4[4];
#pragma unroll
    for (int i = 0; i < 4; ++i) { q4[i] = (float)qs[i]; k4[i] = (float)ks[i]; }

    float sq = 0.f, sk = 0.f;
#pragma unroll
    for (int i = 0; i < 4; ++i) { sq += q4[i] * q4[i]; sk += k4[i] * k4[i]; }
#pragma unroll
    for (int msk = 1; msk < 64; msk <<= 1) {
      sq += __shfl_xor(sq, msk);
      sk += __shfl_xor(sk, msk);
    }
    const int wv = tid >> 6;
    if ((tid & 63) == 0) { red[wv] = sq; red[4 + wv] = sk; }
    __syncthreads();
    sq = red[0] + red[1] + red[2] + red[3];
    sk = red[4] + red[5] + red[6] + red[7];

    const float qinv = 1.0f / sqrtf(sq * (1.0f / INNER) + EPS);
    const float kinv = 1.0f / sqrtf(sk * (1.0f / INNER) + EPS);

#pragma unroll
    for (int i = 0; i < 4; ++i) {
      q4[i] = q4[i] * qinv * nqw[e0 + i];
      k4[i] = k4[i] * kinv * nkw[e0 + i];
    }

    const int h = e0 >> 6, d0 = e0 & (HD - 1);
    const float c0 = r[d0],     s0 = r[HD + d0 + 1];
    const float c1 = r[d0 + 2], s1 = r[HD + d0 + 3];

    float qo[4], ko[4];
    qo[0] = q4[0] * c0 - q4[1] * s0;
    qo[1] = q4[0] * s0 + q4[1] * c0;
    qo[2] = q4[2] * c1 - q4[3] * s1;
    qo[3] = q4[2] * s1 + q4[3] * c1;
    ko[0] = k4[0] * c0 - k4[1] * s0;
    ko[1] = k4[0] * s0 + k4[1] * c0;
    ko[2] = k4[2] * c1 - k4[3] * s1;
    ko[3] = k4[2] * s1 + k4[3] * c1;

    const int hist = S - octx[0];
    if (hist > 0 && spos < hist) {
      const float sig = 1.0f / (1.0f + expf(-hks[h]));
      const float sc = 1.0f + sig * (MAX_SCALE - 1.0f);
#pragma unroll
      for (int i = 0; i < 4; ++i) ko[i] *= sc;
    }

    half4v qo4, ko4;
#pragma unroll
    for (int i = 0; i < 4; ++i) {
      qo4[i] = (_Float16)(qo[i] * SCALE_LOG2E);
      ko4[i] = (_Float16)ko[i];
    }
    const size_t obase = ((size_t)(b * NH + h) * S + spos) * HD + d0;
    *(half4v*)(qo_ + obase) = qo4;
    *(half4v*)(ko_ + obase) = ko4;
  } else {
    _Float16* T = (_Float16*)arena;
    const int id = blockIdx.x - 4096;
    const int bh = id & 31, kt = id >> 5;
    const int b = bh >> 4, h = bh & 15;
    const int s0 = kt * 64;
#pragma unroll
    for (int i = 0; i < 2; ++i) {
      int id2 = tid + 256 * i;
      int s = id2 >> 3, c = id2 & 7;
      *(half8*)&T[s * 72 + c * 8] =
          *(const half8*)&qkvh[(size_t)(b * S + s0 + s) * QKVN + 2 * INNER + h * HD + c * 8];
    }
    __syncthreads();
    _Float16* orow = vt + ((size_t)bh * 32 + kt) * 64 * 64;
#pragma unroll
    for (int i = 0; i < 4; ++i) {
      int id2 = tid + 256 * i;
      int d = id2 >> 4, g = id2 & 15;
      int quad = g >> 2, jj = g & 3;
      half4v o;
#pragma unroll
      for (int k = 0; k < 4; ++k) o[k] = T[(jj * 16 + quad * 4 + k) * 72 + d];
      *(half4v*)&orow[d * 64 + g * 4] = o;
    }
  }
}

// ---------------------------------------------------------------------------
// MFMA flash attention (R10 form): 512 thr = 8 waves, 128-row Q tile,
// double-buffered LDS, register prefetch, packed-f16 softmax.
// ---------------------------------------------------------------------------
__global__ __launch_bounds__(512)
void attn_mfma(const _Float16* __restrict__ qb, const _Float16* __restrict__ kb,
               const _Float16* __restrict__ vt, _Float16* __restrict__ attnb) {
  __shared__ _Float16 Kb0[64 * 72], Vb0[64 * 72];
  __shared__ _Float16 Kb1[64 * 72], Vb1[64 * 72];
  const int bh = blockIdx.x;
  const int b = bh >> 4, h = bh & 15;
  const int q0 = blockIdx.y * 128;
  const int tid = threadIdx.x;
  const int wave = tid >> 6, lane = tid & 63, quad = lane >> 4, l16 = lane & 15;

  const _Float16* qbh = qb + (size_t)bh * S * HD;
  const _Float16* kbh = kb + (size_t)bh * S * HD;
  const _Float16* vbh = vt + (size_t)bh * S * HD;

  half8 aq[2];
#pragma unroll
  for (int ks = 0; ks < 2; ++ks)
    aq[ks] = *(const half8*)&qbh[(size_t)(q0 + wave * 16 + l16) * HD + ks * 32 + quad * 8];

  const int rr = tid >> 3, cc = (tid & 7) * 8;
  const _Float16* kptr = kbh + (size_t)rr * HD + cc;
  const _Float16* vptr = vbh + (size_t)rr * 64 + cc;

  half8 kreg = *(const half8*)kptr, vreg = *(const half8*)vptr;   // tile 0
  *(half8*)&Kb0[rr * 72 + cc] = kreg;
  *(half8*)&Vb0[rr * 72 + cc] = vreg;
  kptr += 64 * HD; vptr += 64 * 64;
  kreg = *(const half8*)kptr; vreg = *(const half8*)vptr;         // tile 1
  __syncthreads();

  floatx4 o16[4] = {};
  float mrow = -INFINITY, lrow = 0.f;

  auto compute = [&](const _Float16* Kp, const _Float16* Vp) {
    floatx4 sc[4] = {};
#pragma unroll
    for (int jj = 0; jj < 4; ++jj) {
#pragma unroll
      for (int ks = 0; ks < 2; ++ks) {
        half8 ak = *(const half8*)&Kp[(jj * 16 + l16) * 72 + ks * 32 + quad * 8];
        sc[jj] = __builtin_amdgcn_mfma_f32_16x16x32_f16(ak, aq[ks], sc[jj], 0, 0, 0);
      }
    }

    half2v ph[8];
#pragma unroll
    for (int jj = 0; jj < 4; ++jj) {
      ph[jj * 2]     = pkrtz(sc[jj][0], sc[jj][1]);
      ph[jj * 2 + 1] = pkrtz(sc[jj][2], sc[jj][3]);
    }
    half2v m0 = hmax2(hmax2(ph[0], ph[1]), hmax2(ph[2], ph[3]));
    half2v m1 = hmax2(hmax2(ph[4], ph[5]), hmax2(ph[6], ph[7]));
    half2v mx2 = hmax2(m0, m1);
    int mi = __builtin_bit_cast(int, mx2);
    mx2 = hmax2(mx2, __builtin_bit_cast(half2v, __shfl_xor(mi, 16)));
    mi = __builtin_bit_cast(int, mx2);
    mx2 = hmax2(mx2, __builtin_bit_cast(half2v, __shfl_xor(mi, 32)));
    const float mxf = fmaxf((float)mx2[0], (float)mx2[1]);
    const float mn = fmaxf(mrow, mxf);
    const bool up = mn > mrow;
    const float alpha = up ? exp2f(mrow - mn) : 1.0f;
    mrow = mn;

    const _Float16 mnh = (_Float16)mn;
    half2v mn2; mn2[0] = mnh; mn2[1] = mnh;
    half2v pe[8];
#pragma unroll
    for (int i = 0; i < 8; ++i)
      pe[i] = __builtin_elementwise_exp2(ph[i] - mn2);

    half2v one2; one2[0] = (_Float16)1.f; one2[1] = (_Float16)1.f;
    const fp16x2 one2p = __builtin_bit_cast(fp16x2, one2);
    float rs = 0.f;
#pragma unroll
    for (int i = 0; i < 8; ++i)
      rs = __builtin_amdgcn_fdot2(__builtin_bit_cast(fp16x2, pe[i]), one2p, rs, false);
    rs += __shfl_xor(rs, 16);
    rs += __shfl_xor(rs, 32);
    lrow = lrow * alpha + rs;

    if (__ballot(up)) {
      float alr[4];
#pragma unroll
      for (int r = 0; r < 4; ++r) alr[r] = __shfl(alpha, quad * 4 + r);
#pragma unroll
      for (int jb = 0; jb < 4; ++jb)
#pragma unroll
        for (int r = 0; r < 4; ++r) o16[jb][r] *= alr[r];
    }

    half4v ap[4];
#pragma unroll
    for (int jj = 0; jj < 4; ++jj)
      ap[jj] = __builtin_shufflevector(pe[jj * 2], pe[jj * 2 + 1], 0, 1, 2, 3);

#pragma unroll
    for (int jb = 0; jb < 4; ++jb) {
      half8 v01 = *(const half8*)&Vp[(jb * 16 + l16) * 72 + quad * 16];
      half8 v23 = *(const half8*)&Vp[(jb * 16 + l16) * 72 + quad * 16 + 8];
      half4v b0 = __builtin_shufflevector(v01, v01, 0, 1, 2, 3);
      half4v b1 = __builtin_shufflevector(v01, v01, 4, 5, 6, 7);
      half4v b2 = __builtin_shufflevector(v23, v23, 0, 1, 2, 3);
      half4v b3 = __builtin_shufflevector(v23, v23, 4, 5, 6, 7);
      o16[jb] = MFMA16(ap[0], b0, o16[jb]);
      o16[jb] = MFMA16(ap[1], b1, o16[jb]);
      o16[jb] = MFMA16(ap[2], b2, o16[jb]);
      o16[jb] = MFMA16(ap[3], b3, o16[jb]);
    }
  };

  for (int t = 0; t < 32; t += 2) {
    *(half8*)&Kb1[rr * 72 + cc] = kreg;
    *(half8*)&Vb1[rr * 72 + cc] = vreg;
    if (t + 2 < 32) {
      kptr += 64 * HD; vptr += 64 * 64;
      kreg = *(const half8*)kptr; vreg = *(const half8*)vptr;
    }
    compute(Kb0, Vb0);
    __syncthreads();
    if (t + 2 < 32) {
      *(half8*)&Kb0[rr * 72 + cc] = kreg;
      *(half8*)&Vb0[rr * 72 + cc] = vreg;
      if (t + 3 < 32) {
        kptr += 64 * HD; vptr += 64 * 64;
        kreg = *(const half8*)kptr; vreg = *(const half8*)vptr;
      }
    }
    compute(Kb1, Vb1);
    __syncthreads();
  }

  float linv[4];
#pragma unroll
  for (int r = 0; r < 4; ++r) linv[r] = 1.0f / __shfl(lrow, quad * 4 + r);
#pragma unroll
  for (int jb = 0; jb < 4; ++jb) {
#pragma unroll
    for (int r = 0; r < 4; ++r) {
      const int row = q0 + wave * 16 + quad * 4 + r;
      attnb[(size_t)(b * S + row) * INNER + h * HD + jb * 16 + l16] =
          (_Float16)(o16[jb][r] * linv[r]);
    }
  }
}

// ---------------------------------------------------------------------------
extern "C" void kernel_launch(void* const* d_in, const int* in_sizes, int n_in,
                              void* d_out, int out_size, void* d_ws, size_t ws_size,
                              hipStream_t stream) {
  const float* hs    = (const float*)d_in[0];
  const float* rot   = (const float*)d_in[1];
  const float* w_qkv = (const float*)d_in[2];
  const float* b_qkv = (const float*)d_in[3];
  const float* nqw   = (const float*)d_in[4];
  const float* nkw   = (const float*)d_in[5];
  const float* w_out = (const float*)d_in[6];
  const float* b_out = (const float*)d_in[7];
  const float* hks   = (const float*)d_in[8];
  const int*   octx  = (const int*)d_in[9];

  _Float16* hsb   = (_Float16*)d_ws;                 // 0-8 MiB (attnb aliases)
  _Float16* attnb = hsb;
  _Float16* wqkvT = hsb   + (size_t)NTOK * DIM;      // 8-14 MiB
  _Float16* woutT = wqkvT + (size_t)QKVN * DIM;      // 14-16 MiB
  _Float16* qkvh  = woutT + (size_t)DIM * INNER;     // 16-40 MiB
  _Float16* q_h   = qkvh  + (size_t)NTOK * QKVN;     // 40-48 MiB
  _Float16* k_h   = q_h   + (size_t)B * NH * S * HD; // 48-56 MiB
  _Float16* vT    = k_h   + (size_t)B * NH * S * HD; // 56-64 MiB

  prep_all<<<3072, 256, 0, stream>>>(hs, w_qkv, w_out, hsb, wqkvT, woutT);

  gemm_bt<true, _Float16><<<dim3(QKVN / 128, NTOK / 128), 256, 0, stream>>>(
      hsb, wqkvT, b_qkv, qkvh, QKVN, DIM);

  post_all<<<5120, 256, 0, stream>>>(qkvh, rot, nqw, nkw, hks, octx, q_h, k_h, vT);

  attn_mfma<<<dim3(B * NH, S / 128), 512, 0, stream>>>(q_h, k_h, vT, attnb);

  gemm_bt<false, float><<<dim3(DIM / 128, NTOK / 128), 256, 0, stream>>>(
      attnb, woutT, b_out, (float*)d_out, DIM, INNER);
}